// Round 6
// baseline (208.901 us; speedup 1.0000x reference)
//
#include <hip/hip_runtime.h>
#include <math.h>

// Geometry: features [B=8,C=256,H=64,W=64]; outputs [8,2,256,256]
#define HWPX  4096
#define CCH   256
#define NPIX  32768
#define NCHAN 2048
#define NFEAT 8388608

// Workspace layout (floats). Every cell written before read; no memset.
#define A1P_OFF   0                         // 4q x 8slices x NPIX (A1 partials)
#define A2P_OFF   (A1P_OFF + 4*8*NPIX)      // 5q x 8slices x NPIX (A2 partials)
#define CHS_OFF   (A2P_OFF + 5*8*NPIX)      // 2048 bc x 8 window partials (student)
#define CHT_OFF   (CHS_OFF + NCHAN*8)       // teacher
#define OPTD_OFF  (CHT_OFF + NCHAN*8)       // 32768 per-pixel maps
#define HETD_OFF  (OPTD_OFF + NPIX)
#define SSP_OFF   (HETD_OFF + NPIX)
#define TSP_OFF   (SSP_OFF + NPIX)
#define KLP_OFF   (TSP_OFF + NPIX)          // 512 block partials (KL)
#define CL1_OFF   (KLP_OFF + 512)
#define GP0_OFF   (CL1_OFF + 512)           // 128 (kernC1)
#define GP1_OFF   (GP0_OFF + 128)
#define GP2_OFF   (GP1_OFF + 128)
#define DTP_OFF   (GP2_OFF + 128)           // 128 (kernC2D)
#define STP_OFF   (DTP_OFF + 128)
#define CFP_OFF   (STP_OFF + 128)
#define CAP_OFF   (CFP_OFF + 128)
#define CNT_OFF   (CAP_OFF + 128)           // completion counter (armed by C1)

__device__ __forceinline__ float sigmoidf_(float x) { return 1.0f / (1.0f + expf(-x)); }

__device__ __forceinline__ float wred(float v) {
#pragma unroll
  for (int o = 32; o > 0; o >>= 1) v += __shfl_down(v, o, 64);
  return v;
}

__device__ __forceinline__ void upd1(const float4& A, const float4& B, const float4& C,
                                     float4& l2a, float4& ca, float4& l2b, float4& cb)
{
#define U1(K) { \
  float d = A.K - B.K; l2a.K = fmaf(d, d, l2a.K); \
  float p = A.K * B.K; \
  float den = fmaxf(fabsf(A.K) * fabsf(B.K), 1e-8f); \
  ca.K = fmaf(p, __builtin_amdgcn_rcpf(den), ca.K); \
  float d2 = A.K - C.K; l2b.K = fmaf(d2, d2, l2b.K); \
  float p2 = A.K * C.K; \
  float dn2 = fmaxf(fabsf(A.K) * fabsf(C.K), 1e-8f); \
  cb.K = fmaf(p2, __builtin_amdgcn_rcpf(dn2), cb.K); }
  U1(x) U1(y) U1(z) U1(w)
#undef U1
}

__device__ __forceinline__ void upd2(const float4& S, const float4& T,
                                     float4& ssq, float4& ssm, float4& smx,
                                     float4& tsm, float4& tmx)
{
#define U2(K) { \
  float ds = S.K - T.K; ssq.K = fmaf(ds, ds, ssq.K); \
  ssm.K += S.K; tsm.K += T.K; \
  smx.K = fmaxf(smx.K, S.K); tmx.K = fmaxf(tmx.K, T.K); }
  U2(x) U2(y) U2(z) U2(w)
#undef U2
}

// ---------- Kernel BIG: A1 | A2 | KL by block range --------------------------
// A-phase tiling (2KB-contiguity version): block = 512-px window x 32 channels.
// Wave owns 8 channels; per channel it issues TWO ADJACENT 1KB wave-loads per
// stream (lane quads at lane*4 and 256+lane*4) -> 2KB contiguous span per
// stream per row-visit (R5 was 1KB at 16KB stride; BW scaled with chunk size
// across R1/R2/R3, so this targets DRAM page-activate efficiency).
// blocks [0,512):     A1 (opt_t1/opt_t2/sar_t2 -> diff-map partials)
// blocks [512,1024):  A2 (student/teacher stats + channel sums)
// blocks [1024,1536): KL
__global__ __launch_bounds__(256) void kernBIG(
    const float* __restrict__ o1p, const float* __restrict__ o2p,
    const float* __restrict__ srp,
    const float* __restrict__ stu, const float* __restrict__ tea,
    const float* __restrict__ so,  const float* __restrict__ to,
    float* __restrict__ ws)
{
  const int bid = blockIdx.x;
  const int tid = threadIdx.x, lane = tid & 63, w = tid >> 6;
  __shared__ float lds[4][5][512];   // 40 KB (A1 uses 4 planes, A2 uses 5)

  if (bid < 512) {
    // ---------------- A1: diff maps ----------------
    const int pw = bid >> 3, cbk = bid & 7;       // pixel-window / channel-slice
    const int b = pw >> 3, wdw = pw & 7;
    const int c0 = cbk * 32 + w * 8;
    size_t idx = ((size_t)(b * CCH + c0)) * HWPX + wdw * 512 + lane * 4;

    float4 l2aA={0,0,0,0}, caA={0,0,0,0}, l2bA={0,0,0,0}, cbA={0,0,0,0};
    float4 l2aB={0,0,0,0}, caB={0,0,0,0}, l2bB={0,0,0,0}, cbB={0,0,0,0};

    float4 Aa = *(const float4*)(o1p + idx), Ab = *(const float4*)(o1p + idx + 256);
    float4 Ba = *(const float4*)(o2p + idx), Bb = *(const float4*)(o2p + idx + 256);
    float4 Ca = *(const float4*)(srp + idx), Cb = *(const float4*)(srp + idx + 256);

#pragma unroll
    for (int i = 0; i < 8; ++i) {
      float4 nAa, nAb, nBa, nBb, nCa, nCb;
      if (i < 7) {
        const size_t nx = idx + HWPX;
        nAa = *(const float4*)(o1p + nx); nAb = *(const float4*)(o1p + nx + 256);
        nBa = *(const float4*)(o2p + nx); nBb = *(const float4*)(o2p + nx + 256);
        nCa = *(const float4*)(srp + nx); nCb = *(const float4*)(srp + nx + 256);
      }
      upd1(Aa, Ba, Ca, l2aA, caA, l2bA, cbA);
      upd1(Ab, Bb, Cb, l2aB, caB, l2bB, cbB);
      if (i < 7) {
        Aa = nAa; Ab = nAb; Ba = nBa; Bb = nBb; Ca = nCa; Cb = nCb;
        idx += HWPX;
      }
    }

    *(float4*)&lds[w][0][lane * 4] = l2aA; *(float4*)&lds[w][0][256 + lane * 4] = l2aB;
    *(float4*)&lds[w][1][lane * 4] = caA;  *(float4*)&lds[w][1][256 + lane * 4] = caB;
    *(float4*)&lds[w][2][lane * 4] = l2bA; *(float4*)&lds[w][2][256 + lane * 4] = l2bB;
    *(float4*)&lds[w][3][lane * 4] = cbA;  *(float4*)&lds[w][3][256 + lane * 4] = cbB;
    __syncthreads();

    float* pa = ws + A1P_OFF;
#pragma unroll
    for (int h = 0; h < 2; ++h) {
      const int p = tid + h * 256;
      float s0 = 0.f, s1 = 0.f, s2 = 0.f, s3 = 0.f;
#pragma unroll
      for (int k = 0; k < 4; ++k) {
        s0 += lds[k][0][p]; s1 += lds[k][1][p];
        s2 += lds[k][2][p]; s3 += lds[k][3][p];
      }
      const int gp = pw * 512 + p;
      pa[(0 * 8 + cbk) * NPIX + gp] = s0;
      pa[(1 * 8 + cbk) * NPIX + gp] = s1;
      pa[(2 * 8 + cbk) * NPIX + gp] = s2;
      pa[(3 * 8 + cbk) * NPIX + gp] = s3;
    }

  } else if (bid < 1024) {
    // ---------------- A2: student/teacher stats + channel sums ----------------
    const int bid2 = bid - 512;
    const int pw = bid2 >> 3, cbk = bid2 & 7;
    const int b = pw >> 3, wdw = pw & 7;
    const int c0 = cbk * 32 + w * 8;
    size_t idx = ((size_t)(b * CCH + c0)) * HWPX + wdw * 512 + lane * 4;

    float4 ssqA={0,0,0,0}, ssmA={0,0,0,0}, tsmA={0,0,0,0};
    float4 ssqB={0,0,0,0}, ssmB={0,0,0,0}, tsmB={0,0,0,0};
    float4 smxA={-INFINITY,-INFINITY,-INFINITY,-INFINITY};
    float4 tmxA = smxA, smxB = smxA, tmxB = smxA;
    float chS[8], chT[8];

    float4 Sa = *(const float4*)(stu + idx), Sb = *(const float4*)(stu + idx + 256);
    float4 Ta = *(const float4*)(tea + idx), Tb = *(const float4*)(tea + idx + 256);

#pragma unroll
    for (int i = 0; i < 8; ++i) {
      float4 nSa, nSb, nTa, nTb;
      if (i < 7) {
        const size_t nx = idx + HWPX;
        nSa = *(const float4*)(stu + nx); nSb = *(const float4*)(stu + nx + 256);
        nTa = *(const float4*)(tea + nx); nTb = *(const float4*)(tea + nx + 256);
      }
      upd2(Sa, Ta, ssqA, ssmA, smxA, tsmA, tmxA);
      upd2(Sb, Tb, ssqB, ssmB, smxB, tsmB, tmxB);
      chS[i] = ((Sa.x + Sa.y) + (Sa.z + Sa.w)) + ((Sb.x + Sb.y) + (Sb.z + Sb.w));
      chT[i] = ((Ta.x + Ta.y) + (Ta.z + Ta.w)) + ((Tb.x + Tb.y) + (Tb.z + Tb.w));
      if (i < 7) {
        Sa = nSa; Sb = nSb; Ta = nTa; Tb = nTb;
        idx += HWPX;
      }
    }

    *(float4*)&lds[w][0][lane * 4] = ssqA; *(float4*)&lds[w][0][256 + lane * 4] = ssqB;
    *(float4*)&lds[w][1][lane * 4] = ssmA; *(float4*)&lds[w][1][256 + lane * 4] = ssmB;
    *(float4*)&lds[w][2][lane * 4] = smxA; *(float4*)&lds[w][2][256 + lane * 4] = smxB;
    *(float4*)&lds[w][3][lane * 4] = tsmA; *(float4*)&lds[w][3][256 + lane * 4] = tsmB;
    *(float4*)&lds[w][4][lane * 4] = tmxA; *(float4*)&lds[w][4][256 + lane * 4] = tmxB;

    // per-(b,c) channel-sum partials over this 512-px window
#pragma unroll
    for (int i = 0; i < 8; ++i) {
      float cs = wred(chS[i]);
      float ct = wred(chT[i]);
      if (lane == 0) {
        const int bc = b * CCH + c0 + i;
        ws[CHS_OFF + bc * 8 + wdw] = cs;
        ws[CHT_OFF + bc * 8 + wdw] = ct;
      }
    }
    __syncthreads();

    float* pa = ws + A2P_OFF;
#pragma unroll
    for (int h = 0; h < 2; ++h) {
      const int p = tid + h * 256;
      float s0 = 0.f, s1 = 0.f, s3 = 0.f;
      float m2 = -INFINITY, m4 = -INFINITY;
#pragma unroll
      for (int k = 0; k < 4; ++k) {
        s0 += lds[k][0][p]; s1 += lds[k][1][p]; s3 += lds[k][3][p];
        m2 = fmaxf(m2, lds[k][2][p]);
        m4 = fmaxf(m4, lds[k][4][p]);
      }
      const int gp = pw * 512 + p;
      pa[(0 * 8 + cbk) * NPIX + gp] = s0;  // ssq
      pa[(1 * 8 + cbk) * NPIX + gp] = s1;  // s_sum
      pa[(2 * 8 + cbk) * NPIX + gp] = m2;  // s_max
      pa[(3 * 8 + cbk) * NPIX + gp] = s3;  // t_sum
      pa[(4 * 8 + cbk) * NPIX + gp] = m4;  // t_max
    }

  } else {
    // ---------------- KL: 2-way softmax KL + class1 MSE ----------------
    const int bkl = bid - 1024;                 // 0..511
    const int gid = bkl * 256 + tid;
    const int p4 = gid << 2;
    const int b  = p4 >> 16;
    const int pp = p4 & 65535;
    const int i0 = b * 131072 + pp;

    const float4 s0 = *(const float4*)(so + i0);
    const float4 s1 = *(const float4*)(so + i0 + 65536);
    const float4 t0 = *(const float4*)(to + i0);
    const float4 t1 = *(const float4*)(to + i0 + 65536);

    float kl = 0.f, c1 = 0.f;
#define KLC(S0, S1, T0, T1)                                           \
    {                                                                 \
      float xs = (S1 - S0) * 0.25f;                                   \
      float xt = (T1 - T0) * 0.25f;                                   \
      float lzs = fmaxf(xs, 0.f) + log1pf(expf(-fabsf(xs)));          \
      float lzt = fmaxf(xt, 0.f) + log1pf(expf(-fabsf(xt)));          \
      float ls0 = -lzs, ls1 = xs - lzs;                               \
      float lt0 = -lzt, lt1 = xt - lzt;                               \
      float pt0 = expf(lt0), pt1 = expf(lt1);                         \
      kl += pt0 * (lt0 - ls0) + pt1 * (lt1 - ls1);                    \
      float ps1 = expf(ls1);                                          \
      float dd = ps1 - pt1;                                           \
      c1 += dd * dd;                                                  \
    }
    KLC(s0.x, s1.x, t0.x, t1.x)
    KLC(s0.y, s1.y, t0.y, t1.y)
    KLC(s0.z, s1.z, t0.z, t1.z)
    KLC(s0.w, s1.w, t0.w, t1.w)
#undef KLC

    kl = wred(kl);
    c1 = wred(c1);
    if ((tid & 63) == 0) { lds[0][0][w * 2] = kl; lds[0][0][w * 2 + 1] = c1; }
    __syncthreads();
    if (tid == 0) {
      ws[KLP_OFF + bkl] = lds[0][0][0] + lds[0][0][2] + lds[0][0][4] + lds[0][0][6];
      ws[CL1_OFF + bkl] = lds[0][0][1] + lds[0][0][3] + lds[0][0][5] + lds[0][0][7];
    }
  }
}

// ---------- Kernel C1: cross-slice combine, finalize maps, phase-1 sums ------
__global__ __launch_bounds__(256) void kernC1(
    const float* __restrict__ mk, float* __restrict__ ws)
{
  const int tid = threadIdx.x;
  const int gp = blockIdx.x * 256 + tid;
  if (blockIdx.x == 0 && tid == 0) *(unsigned*)(ws + CNT_OFF) = 0u;  // arm C2D counter
  const float* pA = ws + A1P_OFF;
  const float* pB = ws + A2P_OFF;

  float a0 = 0.f, a1 = 0.f, a2 = 0.f, a3 = 0.f;
  float b0 = 0.f, b1 = 0.f, b3 = 0.f;
  float m2 = -INFINITY, m4 = -INFINITY;
#pragma unroll
  for (int s = 0; s < 8; ++s) {
    a0 += pA[(0 * 8 + s) * NPIX + gp];
    a1 += pA[(1 * 8 + s) * NPIX + gp];
    a2 += pA[(2 * 8 + s) * NPIX + gp];
    a3 += pA[(3 * 8 + s) * NPIX + gp];
    b0 += pB[(0 * 8 + s) * NPIX + gp];
    b1 += pB[(1 * 8 + s) * NPIX + gp];
    m2 = fmaxf(m2, pB[(2 * 8 + s) * NPIX + gp]);
    b3 += pB[(3 * 8 + s) * NPIX + gp];
    m4 = fmaxf(m4, pB[(4 * 8 + s) * NPIX + gp]);
  }

  const float l2o = sqrtf(a0 + 1e-6f);
  const float opt_d = (l2o + 1.0f - a1 * (1.0f / 256.0f)) * sigmoidf_(l2o * 5.0f);
  const float l2h = sqrtf(a2 + 1e-6f);
  const float het_d = (l2h + 1.0f - a3 * (1.0f / 256.0f)) * sigmoidf_(l2h * 5.0f);
  const float ssp = sigmoidf_(b1 * (1.0f / 256.0f) + m2);
  const float tsp = sigmoidf_(b3 * (1.0f / 256.0f) + m4);

  ws[OPTD_OFF + gp] = opt_d;
  ws[HETD_OFF + gp] = het_d;
  ws[SSP_OFF  + gp] = ssp;
  ws[TSP_OFF  + gp] = tsp;

  const float mv = mk[gp];
  float r0 = b0, r1 = mv * mv * b0, r2 = opt_d;
  r0 = wred(r0); r1 = wred(r1); r2 = wred(r2);
  __shared__ float red[4][3];
  const int w = tid >> 6;
  if ((tid & 63) == 0) { red[w][0] = r0; red[w][1] = r1; red[w][2] = r2; }
  __syncthreads();
  if (tid == 0) {
    ws[GP0_OFF + blockIdx.x] = red[0][0] + red[1][0] + red[2][0] + red[3][0];
    ws[GP1_OFF + blockIdx.x] = red[0][1] + red[1][1] + red[2][1] + red[3][1];
    ws[GP2_OFF + blockIdx.x] = red[0][2] + red[1][2] + red[2][2] + red[3][2];
  }
}

// ---------- Kernel C2D: mean-dependent terms + final combine (last block) ----
__global__ __launch_bounds__(256) void kernC2D(float* __restrict__ ws,
                                               float* __restrict__ out)
{
  const int tid = threadIdx.x;
  const int gid = blockIdx.x * 256 + tid;

  // re-derive sum(opt_diff) from the 128 C1 partials
  float v = (tid < 128) ? ws[GP2_OFF + tid] : 0.f;
  v = wred(v);
  __shared__ float smo[4];
  if ((tid & 63) == 0) smo[tid >> 6] = v;
  __syncthreads();
  const float mean_opt = (smo[0] + smo[1] + smo[2] + smo[3]) * (1.0f / 32768.0f);
  const float att_w = sigmoidf_(mean_opt * 10.0f);
  const float thr = mean_opt * 1.5f;

  const float od  = ws[OPTD_OFF + gid];
  const float hd  = ws[HETD_OFF + gid];
  const float ssp = ws[SSP_OFF + gid];
  const float tsp = ws[TSP_OFF + gid];
  const float mask = od > thr ? 1.0f : 0.0f;
  const float wgt = mask * 2.0f + (1.0f - mask) * 0.5f;
  float dt = (hd - od) * wgt; dt *= dt;
  const float amp = 1.0f + att_w * mask;
  float st = (ssp - tsp) * amp; st *= st;

  float cf = 0.f, catt = 0.f;
  if (gid < NCHAN) {
    float s = 0.f, t = 0.f;
#pragma unroll
    for (int k = 0; k < 8; ++k) {
      s += ws[CHS_OFF + gid * 8 + k];
      t += ws[CHT_OFF + gid * 8 + k];
    }
    const float smn = s * (1.0f / 4096.0f);
    const float tmn = t * (1.0f / 4096.0f);
    const float d = smn - tmn;
    cf = d * d;
    const float d2 = sigmoidf_(smn) - sigmoidf_(tmn);
    catt = d2 * d2;
  }

  dt = wred(dt); st = wred(st); cf = wred(cf); catt = wred(catt);
  __shared__ float red[4][4];
  const int w = tid >> 6;
  if ((tid & 63) == 0) { red[w][0] = dt; red[w][1] = st; red[w][2] = cf; red[w][3] = catt; }
  __syncthreads();
  if (tid == 0) {
    __hip_atomic_store(ws + DTP_OFF + blockIdx.x,
                       red[0][0] + red[1][0] + red[2][0] + red[3][0],
                       __ATOMIC_RELAXED, __HIP_MEMORY_SCOPE_AGENT);
    __hip_atomic_store(ws + STP_OFF + blockIdx.x,
                       red[0][1] + red[1][1] + red[2][1] + red[3][1],
                       __ATOMIC_RELAXED, __HIP_MEMORY_SCOPE_AGENT);
    __hip_atomic_store(ws + CFP_OFF + blockIdx.x,
                       red[0][2] + red[1][2] + red[2][2] + red[3][2],
                       __ATOMIC_RELAXED, __HIP_MEMORY_SCOPE_AGENT);
    __hip_atomic_store(ws + CAP_OFF + blockIdx.x,
                       red[0][3] + red[1][3] + red[2][3] + red[3][3],
                       __ATOMIC_RELAXED, __HIP_MEMORY_SCOPE_AGENT);
  }

  // ---- last block performs the final combine ----
  __shared__ bool isLast;
  if (tid == 0) {
    __threadfence();
    unsigned prev = __hip_atomic_fetch_add((unsigned*)(ws + CNT_OFF), 1u,
                                           __ATOMIC_ACQ_REL, __HIP_MEMORY_SCOPE_AGENT);
    isLast = (prev == 127u);
  }
  __syncthreads();
  if (!isLast) return;
  __threadfence();

  __shared__ float sm[4];
  auto bsum = [&](int off, int n) -> float {
    float acc = 0.f;
    for (int i = tid; i < n; i += 256)
      acc += __hip_atomic_load(ws + off + i, __ATOMIC_RELAXED, __HIP_MEMORY_SCOPE_AGENT);
    acc = wred(acc);
    if ((tid & 63) == 0) sm[tid >> 6] = acc;
    __syncthreads();
    const float r = sm[0] + sm[1] + sm[2] + sm[3];
    __syncthreads();
    return r;
  };

  const float ssqg = bsum(GP0_OFF, 128);
  const float ssql = bsum(GP1_OFF, 128);
  const float sopt = bsum(GP2_OFF, 128);
  const float kls  = bsum(KLP_OFF, 512);
  const float c1s  = bsum(CL1_OFF, 512);
  const float dts  = bsum(DTP_OFF, 128);
  const float sts  = bsum(STP_OFF, 128);
  const float cfs  = bsum(CFP_OFF, 128);
  const float cas  = bsum(CAP_OFF, 128);

  if (tid == 0) {
    const float global_loss = ssqg * (1.0f / (float)NFEAT);
    const float local_loss  = ssql * (1.0f / (float)NFEAT);
    const float chan_f      = cfs * (1.0f / (float)NCHAN);
    const float feat = 0.3f * global_loss + 0.5f * local_loss + 0.2f * chan_f;

    const float kl = kls * 2.0f;                 // * T^2 / B = 16/8
    const float c1 = c1s * (2.0f / 524288.0f);
    const float outl = kl + c1;

    const float mo = sopt * (1.0f / 32768.0f);
    const float aw = sigmoidf_(mo * 10.0f);
    const float diff_loss = dts * (1.0f / 32768.0f);
    const float spat_loss = sts * (1.0f / 32768.0f);
    const float chan_att  = cas * (1.0f / (float)NCHAN);

    const float alpha = 0.5f * (1.0f + 0.5f * aw);
    const float beta  = 0.3f * (1.0f - 0.3f * aw);
    const float gamma = 0.2f * (1.0f + 0.5f * aw);
    const float datt = alpha * diff_loss + beta * chan_att + gamma * spat_loss;

    const float total = 0.3f * feat + 0.4f * outl + 0.3f * datt;
    out[0] = total;
    out[1] = feat;
    out[2] = outl;
    out[3] = datt;
  }
}

extern "C" void kernel_launch(void* const* d_in, const int* in_sizes, int n_in,
                              void* d_out, int out_size, void* d_ws, size_t ws_size,
                              hipStream_t stream)
{
  const float* stu = (const float*)d_in[0];
  const float* tea = (const float*)d_in[1];
  const float* so  = (const float*)d_in[2];
  const float* to  = (const float*)d_in[3];
  const float* o1  = (const float*)d_in[4];
  const float* o2  = (const float*)d_in[5];
  const float* sr  = (const float*)d_in[6];
  const float* mk  = (const float*)d_in[7];
  float* ws  = (float*)d_ws;
  float* out = (float*)d_out;

  kernBIG<<<1536, 256, 0, stream>>>(o1, o2, sr, stu, tea, so, to, ws);
  kernC1<<<128, 256, 0, stream>>>(mk, ws);
  kernC2D<<<128, 256, 0, stream>>>(ws, out);
}

// Round 7
// 193.789 us; speedup vs baseline: 1.0780x; 1.0780x over previous
//
#include <hip/hip_runtime.h>
#include <math.h>

// Geometry: features [B=8,C=256,H=64,W=64]; outputs [8,2,256,256]
#define HWPX  4096
#define CCH   256
#define NPIX  32768
#define NCHAN 2048
#define NFEAT 8388608

// Workspace layout (floats). Every cell written before read; no memset.
#define A1P_OFF   0                         // 4q x 8slices x NPIX (A1 partials)
#define A2P_OFF   (A1P_OFF + 4*8*NPIX)      // 5q x 8slices x NPIX (A2 partials)
#define CHS_OFF   (A2P_OFF + 5*8*NPIX)      // 2048 bc x 16 slots (4 wdw x 4 waves)
#define CHT_OFF   (CHS_OFF + NCHAN*16)
#define OPTD_OFF  (CHT_OFF + NCHAN*16)      // 32768 per-pixel maps
#define HETD_OFF  (OPTD_OFF + NPIX)
#define SSP_OFF   (HETD_OFF + NPIX)
#define TSP_OFF   (SSP_OFF + NPIX)
#define KLP_OFF   (TSP_OFF + NPIX)          // 512 block partials (KL)
#define CL1_OFF   (KLP_OFF + 512)
#define GP0_OFF   (CL1_OFF + 512)           // 128 (kernC1)
#define GP1_OFF   (GP0_OFF + 128)
#define GP2_OFF   (GP1_OFF + 128)
#define DTP_OFF   (GP2_OFF + 128)           // 128 (kernC2D)
#define STP_OFF   (DTP_OFF + 128)
#define CFP_OFF   (STP_OFF + 128)
#define CAP_OFF   (CFP_OFF + 128)
#define CNT_OFF   (CAP_OFF + 128)           // completion counter (armed by C1)

// s_waitcnt with vmcnt(N), lgkm/exp unconstrained (gfx9 encoding)
#define WAITVM(N) __builtin_amdgcn_s_waitcnt(0xF70 | (N))

__device__ __forceinline__ void async16(const float* g, float* l) {
  __builtin_amdgcn_global_load_lds(
      (const __attribute__((address_space(1))) void*)g,
      (__attribute__((address_space(3))) void*)l, 16, 0, 0);
}

__device__ __forceinline__ float sigmoidf_(float x) { return 1.0f / (1.0f + expf(-x)); }

__device__ __forceinline__ float wred(float v) {
#pragma unroll
  for (int o = 32; o > 0; o >>= 1) v += __shfl_down(v, o, 64);
  return v;
}

__device__ __forceinline__ void upd1(const float4& A, const float4& B, const float4& C,
                                     float4& l2a, float4& ca, float4& l2b, float4& cb)
{
#define U1(K) { \
  float d = A.K - B.K; l2a.K = fmaf(d, d, l2a.K); \
  float p = A.K * B.K; \
  float den = fmaxf(fabsf(A.K) * fabsf(B.K), 1e-8f); \
  ca.K = fmaf(p, __builtin_amdgcn_rcpf(den), ca.K); \
  float d2 = A.K - C.K; l2b.K = fmaf(d2, d2, l2b.K); \
  float p2 = A.K * C.K; \
  float dn2 = fmaxf(fabsf(A.K) * fabsf(C.K), 1e-8f); \
  cb.K = fmaf(p2, __builtin_amdgcn_rcpf(dn2), cb.K); }
  U1(x) U1(y) U1(z) U1(w)
#undef U1
}

__device__ __forceinline__ void upd2(const float4& S, const float4& T,
                                     float4& ssq, float4& ssm, float4& smx,
                                     float4& tsm, float4& tmx)
{
#define U2(K) { \
  float ds = S.K - T.K; ssq.K = fmaf(ds, ds, ssq.K); \
  ssm.K += S.K; tsm.K += T.K; \
  smx.K = fmaxf(smx.K, S.K); tmx.K = fmaxf(tmx.K, T.K); }
  U2(x) U2(y) U2(z) U2(w)
#undef U2
}

// ---------- Kernel BIG: A1 | A2 | KL by block range --------------------------
// A-phase: block = 1024-px window x 32 channels of one image. Per step (one
// channel) stage one 4KB contiguous chunk per stream into LDS via
// global_load_lds (width 16) -- NO result VGPRs, depth-4 per-wave async
// pipeline (12 x 1KB in flight), manual vmcnt(9/6/3/0). Each wave stages and
// consumes ONLY its own 1KB LDS slice -> zero barriers in the K-loop.
// blocks [0,256):    A1 (opt_t1/opt_t2/sar_t2 -> diff-map partials)
// blocks [256,512):  A2 (student/teacher stats + channel sums)
// blocks [512,1024): KL
__global__ __launch_bounds__(256) void kernBIG(
    const float* __restrict__ o1p, const float* __restrict__ o2p,
    const float* __restrict__ srp,
    const float* __restrict__ stu, const float* __restrict__ tea,
    const float* __restrict__ so,  const float* __restrict__ to,
    float* __restrict__ ws)
{
  const int bid = blockIdx.x;
  const int tid = threadIdx.x, lane = tid & 63, w = tid >> 6;
  __shared__ float sb[4][3][1024];   // 48 KB staging (A1: 3 streams; A2: 2)

  if (bid < 256) {
    // ---------------- A1: diff maps ----------------
    const int b   = bid >> 5;          // image
    const int r   = bid & 31;
    const int wdw = r >> 3;            // 1024-px window
    const int cs  = r & 7;             // 32-channel slice
    const int c0  = cs * 32;
    const size_t base = ((size_t)(b * CCH + c0)) * HWPX + wdw * 1024 + lane * 4;
    const int wo = w * 256;            // this wave's LDS slice

#define STAGE1(d, step) { \
    const size_t o = base + (size_t)(step) * HWPX; \
    async16(o1p + o, &sb[d][0][wo]); \
    async16(o2p + o, &sb[d][1][wo]); \
    async16(srp + o, &sb[d][2][wo]); }

    STAGE1(0, 0) STAGE1(1, 1) STAGE1(2, 2) STAGE1(3, 3)

    float4 l2a = {0,0,0,0}, ca = {0,0,0,0}, l2b = {0,0,0,0}, cb = {0,0,0,0};
    for (int s = 0; s < 32; ++s) {
      const int d = s & 3;
      if (s <= 28)      WAITVM(9);
      else if (s == 29) WAITVM(6);
      else if (s == 30) WAITVM(3);
      else              WAITVM(0);
      __builtin_amdgcn_sched_barrier(0);
      const float4 Av = *(const float4*)&sb[d][0][tid * 4];
      const float4 Bv = *(const float4*)&sb[d][1][tid * 4];
      const float4 Cv = *(const float4*)&sb[d][2][tid * 4];
      upd1(Av, Bv, Cv, l2a, ca, l2b, cb);
      if (s + 4 < 32) STAGE1(d, s + 4);
    }
#undef STAGE1

    const int gp4 = b * HWPX + wdw * 1024 + tid * 4;
    float* pa = ws + A1P_OFF;
    *(float4*)&pa[(0 * 8 + cs) * NPIX + gp4] = l2a;
    *(float4*)&pa[(1 * 8 + cs) * NPIX + gp4] = ca;
    *(float4*)&pa[(2 * 8 + cs) * NPIX + gp4] = l2b;
    *(float4*)&pa[(3 * 8 + cs) * NPIX + gp4] = cb;

  } else if (bid < 512) {
    // ---------------- A2: student/teacher stats + channel sums ----------------
    const int bidA = bid - 256;
    const int b   = bidA >> 5;
    const int r   = bidA & 31;
    const int wdw = r >> 3;
    const int cs  = r & 7;
    const int c0  = cs * 32;
    const size_t base = ((size_t)(b * CCH + c0)) * HWPX + wdw * 1024 + lane * 4;
    const int wo = w * 256;

#define STAGE2(d, step) { \
    const size_t o = base + (size_t)(step) * HWPX; \
    async16(stu + o, &sb[d][0][wo]); \
    async16(tea + o, &sb[d][1][wo]); }

    STAGE2(0, 0) STAGE2(1, 1) STAGE2(2, 2) STAGE2(3, 3)

    float4 ssq = {0,0,0,0}, ssm = {0,0,0,0}, tsm = {0,0,0,0};
    float4 smx = {-INFINITY,-INFINITY,-INFINITY,-INFINITY};
    float4 tmx = smx;
    for (int s = 0; s < 32; ++s) {
      const int d = s & 3;
      if (s <= 28)      WAITVM(6);
      else if (s == 29) WAITVM(4);
      else if (s == 30) WAITVM(2);
      else              WAITVM(0);
      __builtin_amdgcn_sched_barrier(0);
      const float4 Sv = *(const float4*)&sb[d][0][tid * 4];
      const float4 Tv = *(const float4*)&sb[d][1][tid * 4];
      upd2(Sv, Tv, ssq, ssm, smx, tsm, tmx);
      // per-(b,c) window sums (this channel)
      float csm = (Sv.x + Sv.y) + (Sv.z + Sv.w);
      float ctm = (Tv.x + Tv.y) + (Tv.z + Tv.w);
      csm = wred(csm); ctm = wred(ctm);
      if (lane == 0) {
        const int bc = b * CCH + c0 + s;
        ws[CHS_OFF + bc * 16 + wdw * 4 + w] = csm;
        ws[CHT_OFF + bc * 16 + wdw * 4 + w] = ctm;
      }
      if (s + 4 < 32) STAGE2(d, s + 4);
    }
#undef STAGE2

    const int gp4 = b * HWPX + wdw * 1024 + tid * 4;
    float* pa = ws + A2P_OFF;
    *(float4*)&pa[(0 * 8 + cs) * NPIX + gp4] = ssq;
    *(float4*)&pa[(1 * 8 + cs) * NPIX + gp4] = ssm;
    *(float4*)&pa[(2 * 8 + cs) * NPIX + gp4] = smx;
    *(float4*)&pa[(3 * 8 + cs) * NPIX + gp4] = tsm;
    *(float4*)&pa[(4 * 8 + cs) * NPIX + gp4] = tmx;

  } else {
    // ---------------- KL: 2-way softmax KL + class1 MSE ----------------
    const int bkl = bid - 512;                 // 0..511
    const int gid = bkl * 256 + tid;
    const int p4 = gid << 2;
    const int b  = p4 >> 16;
    const int pp = p4 & 65535;
    const int i0 = b * 131072 + pp;

    const float4 s0 = *(const float4*)(so + i0);
    const float4 s1 = *(const float4*)(so + i0 + 65536);
    const float4 t0 = *(const float4*)(to + i0);
    const float4 t1 = *(const float4*)(to + i0 + 65536);

    float kl = 0.f, c1 = 0.f;
#define KLC(S0, S1, T0, T1)                                           \
    {                                                                 \
      float xs = (S1 - S0) * 0.25f;                                   \
      float xt = (T1 - T0) * 0.25f;                                   \
      float lzs = fmaxf(xs, 0.f) + log1pf(expf(-fabsf(xs)));          \
      float lzt = fmaxf(xt, 0.f) + log1pf(expf(-fabsf(xt)));          \
      float ls0 = -lzs, ls1 = xs - lzs;                               \
      float lt0 = -lzt, lt1 = xt - lzt;                               \
      float pt0 = expf(lt0), pt1 = expf(lt1);                         \
      kl += pt0 * (lt0 - ls0) + pt1 * (lt1 - ls1);                    \
      float ps1 = expf(ls1);                                          \
      float dd = ps1 - pt1;                                           \
      c1 += dd * dd;                                                  \
    }
    KLC(s0.x, s1.x, t0.x, t1.x)
    KLC(s0.y, s1.y, t0.y, t1.y)
    KLC(s0.z, s1.z, t0.z, t1.z)
    KLC(s0.w, s1.w, t0.w, t1.w)
#undef KLC

    kl = wred(kl);
    c1 = wred(c1);
    if ((tid & 63) == 0) { sb[0][0][w * 2] = kl; sb[0][0][w * 2 + 1] = c1; }
    __syncthreads();
    if (tid == 0) {
      ws[KLP_OFF + bkl] = sb[0][0][0] + sb[0][0][2] + sb[0][0][4] + sb[0][0][6];
      ws[CL1_OFF + bkl] = sb[0][0][1] + sb[0][0][3] + sb[0][0][5] + sb[0][0][7];
    }
  }
}

// ---------- Kernel C1: cross-slice combine, finalize maps, phase-1 sums ------
__global__ __launch_bounds__(256) void kernC1(
    const float* __restrict__ mk, float* __restrict__ ws)
{
  const int tid = threadIdx.x;
  const int gp = blockIdx.x * 256 + tid;
  if (blockIdx.x == 0 && tid == 0) *(unsigned*)(ws + CNT_OFF) = 0u;  // arm C2D counter
  const float* pA = ws + A1P_OFF;
  const float* pB = ws + A2P_OFF;

  float a0 = 0.f, a1 = 0.f, a2 = 0.f, a3 = 0.f;
  float b0 = 0.f, b1 = 0.f, b3 = 0.f;
  float m2 = -INFINITY, m4 = -INFINITY;
#pragma unroll
  for (int s = 0; s < 8; ++s) {
    a0 += pA[(0 * 8 + s) * NPIX + gp];
    a1 += pA[(1 * 8 + s) * NPIX + gp];
    a2 += pA[(2 * 8 + s) * NPIX + gp];
    a3 += pA[(3 * 8 + s) * NPIX + gp];
    b0 += pB[(0 * 8 + s) * NPIX + gp];
    b1 += pB[(1 * 8 + s) * NPIX + gp];
    m2 = fmaxf(m2, pB[(2 * 8 + s) * NPIX + gp]);
    b3 += pB[(3 * 8 + s) * NPIX + gp];
    m4 = fmaxf(m4, pB[(4 * 8 + s) * NPIX + gp]);
  }

  const float l2o = sqrtf(a0 + 1e-6f);
  const float opt_d = (l2o + 1.0f - a1 * (1.0f / 256.0f)) * sigmoidf_(l2o * 5.0f);
  const float l2h = sqrtf(a2 + 1e-6f);
  const float het_d = (l2h + 1.0f - a3 * (1.0f / 256.0f)) * sigmoidf_(l2h * 5.0f);
  const float ssp = sigmoidf_(b1 * (1.0f / 256.0f) + m2);
  const float tsp = sigmoidf_(b3 * (1.0f / 256.0f) + m4);

  ws[OPTD_OFF + gp] = opt_d;
  ws[HETD_OFF + gp] = het_d;
  ws[SSP_OFF  + gp] = ssp;
  ws[TSP_OFF  + gp] = tsp;

  const float mv = mk[gp];
  float r0 = b0, r1 = mv * mv * b0, r2 = opt_d;
  r0 = wred(r0); r1 = wred(r1); r2 = wred(r2);
  __shared__ float red[4][3];
  const int w = tid >> 6;
  if ((tid & 63) == 0) { red[w][0] = r0; red[w][1] = r1; red[w][2] = r2; }
  __syncthreads();
  if (tid == 0) {
    ws[GP0_OFF + blockIdx.x] = red[0][0] + red[1][0] + red[2][0] + red[3][0];
    ws[GP1_OFF + blockIdx.x] = red[0][1] + red[1][1] + red[2][1] + red[3][1];
    ws[GP2_OFF + blockIdx.x] = red[0][2] + red[1][2] + red[2][2] + red[3][2];
  }
}

// ---------- Kernel C2D: mean-dependent terms + final combine (last block) ----
__global__ __launch_bounds__(256) void kernC2D(float* __restrict__ ws,
                                               float* __restrict__ out)
{
  const int tid = threadIdx.x;
  const int gid = blockIdx.x * 256 + tid;

  // re-derive sum(opt_diff) from the 128 C1 partials
  float v = (tid < 128) ? ws[GP2_OFF + tid] : 0.f;
  v = wred(v);
  __shared__ float smo[4];
  if ((tid & 63) == 0) smo[tid >> 6] = v;
  __syncthreads();
  const float mean_opt = (smo[0] + smo[1] + smo[2] + smo[3]) * (1.0f / 32768.0f);
  const float att_w = sigmoidf_(mean_opt * 10.0f);
  const float thr = mean_opt * 1.5f;

  const float od  = ws[OPTD_OFF + gid];
  const float hd  = ws[HETD_OFF + gid];
  const float ssp = ws[SSP_OFF + gid];
  const float tsp = ws[TSP_OFF + gid];
  const float mask = od > thr ? 1.0f : 0.0f;
  const float wgt = mask * 2.0f + (1.0f - mask) * 0.5f;
  float dt = (hd - od) * wgt; dt *= dt;
  const float amp = 1.0f + att_w * mask;
  float st = (ssp - tsp) * amp; st *= st;

  float cf = 0.f, catt = 0.f;
  if (gid < NCHAN) {
    float s = 0.f, t = 0.f;
#pragma unroll
    for (int k = 0; k < 16; ++k) {
      s += ws[CHS_OFF + gid * 16 + k];
      t += ws[CHT_OFF + gid * 16 + k];
    }
    const float smn = s * (1.0f / 4096.0f);
    const float tmn = t * (1.0f / 4096.0f);
    const float d = smn - tmn;
    cf = d * d;
    const float d2 = sigmoidf_(smn) - sigmoidf_(tmn);
    catt = d2 * d2;
  }

  dt = wred(dt); st = wred(st); cf = wred(cf); catt = wred(catt);
  __shared__ float red[4][4];
  const int w = tid >> 6;
  if ((tid & 63) == 0) { red[w][0] = dt; red[w][1] = st; red[w][2] = cf; red[w][3] = catt; }
  __syncthreads();
  if (tid == 0) {
    __hip_atomic_store(ws + DTP_OFF + blockIdx.x,
                       red[0][0] + red[1][0] + red[2][0] + red[3][0],
                       __ATOMIC_RELAXED, __HIP_MEMORY_SCOPE_AGENT);
    __hip_atomic_store(ws + STP_OFF + blockIdx.x,
                       red[0][1] + red[1][1] + red[2][1] + red[3][1],
                       __ATOMIC_RELAXED, __HIP_MEMORY_SCOPE_AGENT);
    __hip_atomic_store(ws + CFP_OFF + blockIdx.x,
                       red[0][2] + red[1][2] + red[2][2] + red[3][2],
                       __ATOMIC_RELAXED, __HIP_MEMORY_SCOPE_AGENT);
    __hip_atomic_store(ws + CAP_OFF + blockIdx.x,
                       red[0][3] + red[1][3] + red[2][3] + red[3][3],
                       __ATOMIC_RELAXED, __HIP_MEMORY_SCOPE_AGENT);
  }

  // ---- last block performs the final combine ----
  __shared__ bool isLast;
  if (tid == 0) {
    __threadfence();
    unsigned prev = __hip_atomic_fetch_add((unsigned*)(ws + CNT_OFF), 1u,
                                           __ATOMIC_ACQ_REL, __HIP_MEMORY_SCOPE_AGENT);
    isLast = (prev == 127u);
  }
  __syncthreads();
  if (!isLast) return;
  __threadfence();

  __shared__ float sm[4];
  auto bsum = [&](int off, int n) -> float {
    float acc = 0.f;
    for (int i = tid; i < n; i += 256)
      acc += __hip_atomic_load(ws + off + i, __ATOMIC_RELAXED, __HIP_MEMORY_SCOPE_AGENT);
    acc = wred(acc);
    if ((tid & 63) == 0) sm[tid >> 6] = acc;
    __syncthreads();
    const float r = sm[0] + sm[1] + sm[2] + sm[3];
    __syncthreads();
    return r;
  };

  const float ssqg = bsum(GP0_OFF, 128);
  const float ssql = bsum(GP1_OFF, 128);
  const float sopt = bsum(GP2_OFF, 128);
  const float kls  = bsum(KLP_OFF, 512);
  const float c1s  = bsum(CL1_OFF, 512);
  const float dts  = bsum(DTP_OFF, 128);
  const float sts  = bsum(STP_OFF, 128);
  const float cfs  = bsum(CFP_OFF, 128);
  const float cas  = bsum(CAP_OFF, 128);

  if (tid == 0) {
    const float global_loss = ssqg * (1.0f / (float)NFEAT);
    const float local_loss  = ssql * (1.0f / (float)NFEAT);
    const float chan_f      = cfs * (1.0f / (float)NCHAN);
    const float feat = 0.3f * global_loss + 0.5f * local_loss + 0.2f * chan_f;

    const float kl = kls * 2.0f;                 // * T^2 / B = 16/8
    const float c1 = c1s * (2.0f / 524288.0f);
    const float outl = kl + c1;

    const float mo = sopt * (1.0f / 32768.0f);
    const float aw = sigmoidf_(mo * 10.0f);
    const float diff_loss = dts * (1.0f / 32768.0f);
    const float spat_loss = sts * (1.0f / 32768.0f);
    const float chan_att  = cas * (1.0f / (float)NCHAN);

    const float alpha = 0.5f * (1.0f + 0.5f * aw);
    const float beta  = 0.3f * (1.0f - 0.3f * aw);
    const float gamma = 0.2f * (1.0f + 0.5f * aw);
    const float datt = alpha * diff_loss + beta * chan_att + gamma * spat_loss;

    const float total = 0.3f * feat + 0.4f * outl + 0.3f * datt;
    out[0] = total;
    out[1] = feat;
    out[2] = outl;
    out[3] = datt;
  }
}

extern "C" void kernel_launch(void* const* d_in, const int* in_sizes, int n_in,
                              void* d_out, int out_size, void* d_ws, size_t ws_size,
                              hipStream_t stream)
{
  const float* stu = (const float*)d_in[0];
  const float* tea = (const float*)d_in[1];
  const float* so  = (const float*)d_in[2];
  const float* to  = (const float*)d_in[3];
  const float* o1  = (const float*)d_in[4];
  const float* o2  = (const float*)d_in[5];
  const float* sr  = (const float*)d_in[6];
  const float* mk  = (const float*)d_in[7];
  float* ws  = (float*)d_ws;
  float* out = (float*)d_out;

  kernBIG<<<1024, 256, 0, stream>>>(o1, o2, sr, stu, tea, so, to, ws);
  kernC1<<<128, 256, 0, stream>>>(mk, ws);
  kernC2D<<<128, 256, 0, stream>>>(ws, out);
}